// Round 2
// baseline (5376.358 us; speedup 1.0000x reference)
//
#include <hip/hip_runtime.h>
#include <cstdint>
#include <cstddef>

// SingleLayerLSTM: B=128, T=2048, D=64, H=256, O=32.
// v12 = v11 + XCD-local L2 exchange.
// R1 post-mortem: v11 (spec poll + raw barriers) was flat -> the step is
// dominated by the agent-scope (sc1) round-trip: polls and publishes
// bypass L2 entirely (WRITE_SIZE 288MB ~= all publish traffic egressing
// L2), giving a ~1000cy discovery quantum that a hoisted load can't beat.
// v12 attacks the latency itself:
//  (1) Block swizzle: group g2's 4 quarter-blocks all get blockIdx % 8
//      equal -> same XCD (round-robin mapping, perf-only assumption).
//  (2) Dual publish: fast sc0 store to xf (lands in the shared XCD L2,
//      ~200cy visibility) + agent store to disjoint xa (fallback).
//  (3) Poll: sc0 loads on xf (L2 hit ~200cy); every 8th try escalates to
//      agent load on xa. Bad mapping -> xf polls are stale-cached forever
//      (tag never matches, harmless) and xa delivers: correct, just slow.
//      Tag-in-u64 equality makes stale/replay/interleave all safe; 0xAA
//      poison never matches -> no init, graph-replay safe.
//  (4) u over-fetch (4 blocks read same rows) now L2-shared per XCD.
// Everything else identical to v11: 256 blocks x 512 thr, 80 fp16-pair
// weight VGPRs shared by both items, shadow UOWN/y-pipeline, raw lgkm
// barriers. ws: xf 256KB @0, xa 256KB @256KB.

#define HH 256
#define DD 64
#define TT 2048
#define OO 32

typedef _Float16 f16x2 __attribute__((ext_vector_type(2)));

__device__ __forceinline__ f16x2 b2h(int v) { return __builtin_bit_cast(f16x2, v); }
__device__ __forceinline__ int h2b(f16x2 v) { return __builtin_bit_cast(int, v); }
__device__ __forceinline__ unsigned pk32(float a, float b) {
  f16x2 v; v.x = (_Float16)a; v.y = (_Float16)b;
  return __builtin_bit_cast(unsigned, v);
}

#if __has_builtin(__builtin_amdgcn_fdot2)
__device__ __forceinline__ float fdot2(f16x2 a, f16x2 b, float c) {
  return __builtin_amdgcn_fdot2(a, b, c, false);
}
#else
__device__ __forceinline__ float fdot2(f16x2 a, f16x2 b, float c) {
  return fmaf((float)a.y, (float)b.y, fmaf((float)a.x, (float)b.x, c));
}
#endif

__device__ __forceinline__ float frcp(float x) { return __builtin_amdgcn_rcpf(x); }
__device__ __forceinline__ float sigm(float x)  { return frcp(1.0f + __expf(-x)); }
__device__ __forceinline__ float tanhf_(float x){ return 1.0f - 2.0f * frcp(1.0f + __expf(2.0f * x)); }

// sc0-only global ops: bypass L1, hit/land in the XCD-local L2.
__device__ __forceinline__ void st_sc0(unsigned long long* p, unsigned long long v) {
  asm volatile("global_store_dwordx2 %0, %1, off sc0" :: "v"(p), "v"(v) : "memory");
}
__device__ __forceinline__ unsigned long long ld_sc0(const unsigned long long* p) {
  unsigned long long v;
  asm volatile("global_load_dwordx2 %0, %1, off sc0\n\ts_waitcnt vmcnt(0)"
               : "=v"(v) : "v"(p) : "memory");
  return v;
}

// LDS-only drain + raw barrier: global loads/stores stay in flight.
#define BAR_LGKM() do { \
  asm volatile("s_waitcnt lgkmcnt(0)" ::: "memory"); \
  __builtin_amdgcn_s_barrier(); \
  asm volatile("" ::: "memory"); \
} while (0)

#define XOR_ADD8(x) do { \
  x += __shfl_xor(x, 1); x += __shfl_xor(x, 2); x += __shfl_xor(x, 4); \
} while (0)

// u(8 rows) + own-h(8 rows) partial for one item; overwrites F,I,Z,R
#define UOWN(X, F, I, Z, R) do { \
  const int4 uv_ = *(const int4*)&(X)[rq * 8]; \
  const int4 ov_ = *(const int4*)&(X)[64 + rq * 8]; \
  f16x2 u0_=b2h(uv_.x),u1_=b2h(uv_.y),u2_=b2h(uv_.z),u3_=b2h(uv_.w); \
  f16x2 o0_=b2h(ov_.x),o1_=b2h(ov_.y),o2_=b2h(ov_.z),o3_=b2h(ov_.w); \
  F = fdot2(b2h(w2u[ 0]),u0_,0.0f); F = fdot2(b2h(w2u[ 1]),u1_,F); \
  F = fdot2(b2h(w2u[ 2]),u2_,F);    F = fdot2(b2h(w2u[ 3]),u3_,F); \
  F = fdot2(b2h(w2o[ 0]),o0_,F);    F = fdot2(b2h(w2o[ 1]),o1_,F); \
  F = fdot2(b2h(w2o[ 2]),o2_,F);    F = fdot2(b2h(w2o[ 3]),o3_,F); \
  I = fdot2(b2h(w2u[ 4]),u0_,0.0f); I = fdot2(b2h(w2u[ 5]),u1_,I); \
  I = fdot2(b2h(w2u[ 6]),u2_,I);    I = fdot2(b2h(w2u[ 7]),u3_,I); \
  I = fdot2(b2h(w2o[ 4]),o0_,I);    I = fdot2(b2h(w2o[ 5]),o1_,I); \
  I = fdot2(b2h(w2o[ 6]),o2_,I);    I = fdot2(b2h(w2o[ 7]),o3_,I); \
  Z = fdot2(b2h(w2u[ 8]),u0_,0.0f); Z = fdot2(b2h(w2u[ 9]),u1_,Z); \
  Z = fdot2(b2h(w2u[10]),u2_,Z);    Z = fdot2(b2h(w2u[11]),u3_,Z); \
  Z = fdot2(b2h(w2o[ 8]),o0_,Z);    Z = fdot2(b2h(w2o[ 9]),o1_,Z); \
  Z = fdot2(b2h(w2o[10]),o2_,Z);    Z = fdot2(b2h(w2o[11]),o3_,Z); \
  R = fdot2(b2h(w2u[12]),u0_,0.0f); R = fdot2(b2h(w2u[13]),u1_,R); \
  R = fdot2(b2h(w2u[14]),u2_,R);    R = fdot2(b2h(w2u[15]),u3_,R); \
  R = fdot2(b2h(w2o[12]),o0_,R);    R = fdot2(b2h(w2o[13]),o1_,R); \
  R = fdot2(b2h(w2o[14]),o2_,R);    R = fdot2(b2h(w2o[15]),o3_,R); \
} while (0)

// partner-h (24 rows) accumulate into F,I,Z,R
#define PDOT(X, F, I, Z, R) do { \
  const int4* pp_ = (const int4*)&(X)[128 + rq * 24]; \
  int4 v0_ = pp_[0], v1_ = pp_[1], v2_ = pp_[2]; \
  f16x2 h0_=b2h(v0_.x),h1_=b2h(v0_.y),h2_ =b2h(v0_.z),h3_ =b2h(v0_.w); \
  f16x2 h4_=b2h(v1_.x),h5_=b2h(v1_.y),h6_ =b2h(v1_.z),h7_ =b2h(v1_.w); \
  f16x2 h8_=b2h(v2_.x),h9_=b2h(v2_.y),h10_=b2h(v2_.z),h11_=b2h(v2_.w); \
  F=fdot2(b2h(w2p[ 0]),h0_,F); F=fdot2(b2h(w2p[ 1]),h1_,F); \
  F=fdot2(b2h(w2p[ 2]),h2_,F); F=fdot2(b2h(w2p[ 3]),h3_,F); \
  F=fdot2(b2h(w2p[ 4]),h4_,F); F=fdot2(b2h(w2p[ 5]),h5_,F); \
  F=fdot2(b2h(w2p[ 6]),h6_,F); F=fdot2(b2h(w2p[ 7]),h7_,F); \
  F=fdot2(b2h(w2p[ 8]),h8_,F); F=fdot2(b2h(w2p[ 9]),h9_,F); \
  F=fdot2(b2h(w2p[10]),h10_,F);F=fdot2(b2h(w2p[11]),h11_,F); \
  I=fdot2(b2h(w2p[12]),h0_,I); I=fdot2(b2h(w2p[13]),h1_,I); \
  I=fdot2(b2h(w2p[14]),h2_,I); I=fdot2(b2h(w2p[15]),h3_,I); \
  I=fdot2(b2h(w2p[16]),h4_,I); I=fdot2(b2h(w2p[17]),h5_,I); \
  I=fdot2(b2h(w2p[18]),h6_,I); I=fdot2(b2h(w2p[19]),h7_,I); \
  I=fdot2(b2h(w2p[20]),h8_,I); I=fdot2(b2h(w2p[21]),h9_,I); \
  I=fdot2(b2h(w2p[22]),h10_,I);I=fdot2(b2h(w2p[23]),h11_,I); \
  Z=fdot2(b2h(w2p[24]),h0_,Z); Z=fdot2(b2h(w2p[25]),h1_,Z); \
  Z=fdot2(b2h(w2p[26]),h2_,Z); Z=fdot2(b2h(w2p[27]),h3_,Z); \
  Z=fdot2(b2h(w2p[28]),h4_,Z); Z=fdot2(b2h(w2p[29]),h5_,Z); \
  Z=fdot2(b2h(w2p[30]),h6_,Z); Z=fdot2(b2h(w2p[31]),h7_,Z); \
  Z=fdot2(b2h(w2p[32]),h8_,Z); Z=fdot2(b2h(w2p[33]),h9_,Z); \
  Z=fdot2(b2h(w2p[34]),h10_,Z);Z=fdot2(b2h(w2p[35]),h11_,Z); \
  R=fdot2(b2h(w2p[36]),h0_,R); R=fdot2(b2h(w2p[37]),h1_,R); \
  R=fdot2(b2h(w2p[38]),h2_,R); R=fdot2(b2h(w2p[39]),h3_,R); \
  R=fdot2(b2h(w2p[40]),h4_,R); R=fdot2(b2h(w2p[41]),h5_,R); \
  R=fdot2(b2h(w2p[42]),h6_,R); R=fdot2(b2h(w2p[43]),h7_,R); \
  R=fdot2(b2h(w2p[44]),h8_,R); R=fdot2(b2h(w2p[45]),h9_,R); \
  R=fdot2(b2h(w2p[46]),h10_,R);R=fdot2(b2h(w2p[47]),h11_,R); \
} while (0)

// y-partials for one item from the permuted h region of X
#define YPART(X, OUTSLOT) do { \
  const int2* hq_ = (const int2*)&(X)[64 + jc * 16]; \
  int2 h0_ = hq_[0], h1_ = hq_[1], h2_ = hq_[2], h3_ = hq_[3]; \
  const int4* wp_ = (const int4*)&wopk[(jc * 8 + o) * 8]; \
  int4 wa_ = wp_[0], wb_ = wp_[1]; \
  float ya_ = 0.0f; \
  ya_ = fdot2(b2h(wa_.x), b2h(h0_.x), ya_); \
  ya_ = fdot2(b2h(wa_.y), b2h(h0_.y), ya_); \
  ya_ = fdot2(b2h(wa_.z), b2h(h1_.x), ya_); \
  ya_ = fdot2(b2h(wa_.w), b2h(h1_.y), ya_); \
  ya_ = fdot2(b2h(wb_.x), b2h(h2_.x), ya_); \
  ya_ = fdot2(b2h(wb_.y), b2h(h2_.y), ya_); \
  ya_ = fdot2(b2h(wb_.z), b2h(h3_.x), ya_); \
  ya_ = fdot2(b2h(wb_.w), b2h(h3_.y), ya_); \
  OUTSLOT = ya_; \
} while (0)

__global__ __launch_bounds__(512, 2)
void lstm_pair(const float* __restrict__ u,    const float* __restrict__ x0,
               const float* __restrict__ kfiz, const float* __restrict__ bfiz,
               const float* __restrict__ kr,   const float* __restrict__ br,
               const float* __restrict__ wout, const float* __restrict__ bout,
               float* __restrict__ out, unsigned long long* __restrict__ xh)
{
  const int tid = threadIdx.x;
  // XCD swizzle: group g2's 4 members all have blockIdx%8 == g2&7 ->
  // same XCD under round-robin dispatch. Bijective on [0,256).
  const int pb  = blockIdx.x;
  const int g2  = (pb & 7) * 8 + (pb >> 5);  // item pair: items 2g2, 2g2+1
  const int q4  = (pb >> 3) & 3;             // quarter
  const int c   = tid >> 3;                  // channel within quarter [0,64)
  const int rq  = tid & 7;                   // row slice
  const int cg  = q4 * 64 + c;               // global channel

  unsigned long long* xf = xh;               // fast lane: sc0, XCD L2
  unsigned long long* xa = xh + 32768;       // fallback: agent scope

  // per (parity,item): [0,64) u | [64,128) own h | [128,320) partner h (P-order)
  __shared__ __align__(16) _Float16 uh[2][2][320];
  __shared__ float yred[2][2][8][17];
  __shared__ __align__(16) int wopk[1024];

  // ---- register-resident weights (80 pairs, shared by both items) ----
  int w2u[16], w2o[16], w2p[48];
#pragma unroll
  for (int g = 0; g < 4; ++g) {
    const float* colp = (g < 3) ? (kfiz + g * HH + cg) : (kr + cg);
    const int cst = (g < 3) ? 3 * HH : HH;
#pragma unroll
    for (int k = 0; k < 4; ++k) {
      f16x2 v;
      v.x = (_Float16)colp[(rq * 8 + 2 * k    ) * cst];
      v.y = (_Float16)colp[(rq * 8 + 2 * k + 1) * cst];
      w2u[g * 4 + k] = h2b(v);
      f16x2 w;
      w.x = (_Float16)colp[(DD + q4 * 64 + rq * 8 + 2 * k    ) * cst];
      w.y = (_Float16)colp[(DD + q4 * 64 + rq * 8 + 2 * k + 1) * cst];
      w2o[g * 4 + k] = h2b(w);
    }
#pragma unroll
    for (int m = 0; m < 12; ++m) {
      const int j0 = rq * 24 + 2 * m, j1 = j0 + 1;
      const int r0 = DD + (j0 < q4 * 64 ? j0 : j0 + 64);
      const int r1 = DD + (j1 < q4 * 64 ? j1 : j1 + 64);
      f16x2 v;
      v.x = (_Float16)colp[r0 * cst];
      v.y = (_Float16)colp[r1 * cst];
      w2p[g * 12 + m] = h2b(v);
    }
  }
  const float bf_ = bfiz[0 * HH + cg];
  const float bi_ = bfiz[1 * HH + cg];
  const float bz_ = bfiz[2 * HH + cg];
  const float br_ = br[cg];

  // ---- W_out staged permuted (block's 8 out cols; item-invariant) ----
  for (int t = tid; t < 1024; t += 512) {
    const int jc = t >> 6, o = (t >> 3) & 7, k = t & 7;
    const int pos0 = jc * 16 + 2 * k, pos1 = pos0 + 1;
    const int ch0 = (pos0 < 64) ? q4 * 64 + pos0
                                : ((pos0 - 64) < q4 * 64 ? pos0 - 64 : pos0);
    const int ch1 = (pos1 < 64) ? q4 * 64 + pos1
                                : ((pos1 - 64) < q4 * 64 ? pos1 - 64 : pos1);
    f16x2 v;
    v.x = (_Float16)wout[ch0 * OO + q4 * 8 + o];
    v.y = (_Float16)wout[ch1 * OO + q4 * 8 + o];
    wopk[t] = h2b(v);
  }
  const float bo = (tid >= 448 && tid < 464) ? bout[q4 * 8 + ((tid - 448) & 7)] : 0.0f;

  // ---- state init ----
  float cs0 = x0[(size_t)(g2 * 2 + 0) * 512 + 256 + cg];
  float cs1 = x0[(size_t)(g2 * 2 + 1) * 512 + 256 + cg];
  {  // h0, permuted; all 512 lanes cover 2 items x 256 ch
    const int it = tid >> 8, ch = tid & 255;
    const int pos = (ch >= q4 * 64 && ch < q4 * 64 + 64)
                        ? 64 + (ch - q4 * 64)
                        : 128 + (ch < q4 * 64 ? ch : ch - 64);
    uh[0][it][pos] = (_Float16)x0[(size_t)(g2 * 2 + it) * 512 + ch];
  }
  if (tid >= 192 && tid < 320) {   // u_0
    const int l = tid - 192;
    uh[0][l >> 6][l & 63] = (_Float16)u[((size_t)(g2 * 2 + (l >> 6)) * TT) * DD + (l & 63)];
  }
  __syncthreads();

  float a0f, a0i, a0z, a0r, a1f, a1i, a1z, a1r;
  UOWN(uh[0][0], a0f, a0i, a0z, a0r);
  UOWN(uh[0][1], a1f, a1i, a1z, a1r);

  for (int s = 0; s < TT; ++s) {
    const int cur = s & 1, nxt = cur ^ 1;

    // u_{s+1} issued early (lanes 192..319)
    float un = 0.0f;
    if (tid >= 192 && tid < 320 && s + 1 < TT) {
      const int l = tid - 192;
      un = u[((size_t)(g2 * 2 + (l >> 6)) * TT + s + 1) * DD + (l & 63)];
    }

    // ---- A: partner dots, both items ----
    PDOT(uh[cur][0], a0f, a0i, a0z, a0r);
    PDOT(uh[cur][1], a1f, a1i, a1z, a1r);

    // ---- B: reduce + activations ----
    XOR_ADD8(a0f); XOR_ADD8(a0i); XOR_ADD8(a0z); XOR_ADD8(a0r);
    XOR_ADD8(a1f); XOR_ADD8(a1i); XOR_ADD8(a1z); XOR_ADD8(a1r);
    const float f0 = sigm(a0f + bf_), i0 = sigm(a0i + bi_);
    const float z0 = sigm(a0z + bz_), r0 = tanhf_(a0r + br_);
    cs0 = f0 * cs0 + i0 * r0;
    const float hn0 = z0 * tanhf_(cs0);
    const float f1 = sigm(a1f + bf_), i1 = sigm(a1i + bi_);
    const float z1 = sigm(a1z + bz_), r1 = tanhf_(a1r + br_);
    cs1 = f1 * cs1 + i1 * r1;
    const float hn1 = z1 * tanhf_(cs1);

    // ---- C: publish (fast sc0 first, then agent fallback) ----
    const float hn0n = __shfl_down(hn0, 8);   // channel c+1's value (rq kept)
    const float hn1n = __shfl_down(hn1, 8);
    if (rq == 0) {
      uh[nxt][0][64 + c] = (_Float16)hn0;
      uh[nxt][1][64 + c] = (_Float16)hn1;
      if (!(c & 1)) {
        const int pair = q4 * 32 + (c >> 1);
        const unsigned long long tag = (unsigned long long)(s + 1) << 32;
        const size_t i0 = ((size_t)nxt << 14) + (size_t)(g2 * 2 + 0) * 128 + pair;
        const unsigned long long v0 = tag | pk32(hn0, hn0n);
        const unsigned long long v1 = tag | pk32(hn1, hn1n);
        st_sc0(xf + i0, v0);
        st_sc0(xf + i0 + 128, v1);
        __hip_atomic_store(xa + i0, v0, __ATOMIC_RELAXED, __HIP_MEMORY_SCOPE_AGENT);
        __hip_atomic_store(xa + i0 + 128, v1, __ATOMIC_RELAXED, __HIP_MEMORY_SCOPE_AGENT);
      }
    }
    if (tid >= 192 && tid < 320 && s + 1 < TT) {
      const int l = tid - 192;
      uh[nxt][l >> 6][l & 63] = (_Float16)un;
    }
    BAR_LGKM();   // B1: LDS drain only; publish stores stay in flight

    // ---- speculative early poll ISSUE on the fast lane (no waitcnt) ----
    unsigned long long pv = 0;
    const unsigned long long* pf = nullptr;
    if (tid < 192) {
      const int pit = (tid >= 96) ? 1 : 0;
      const int pj  = pit ? tid - 96 : tid;
      const int pidx = (pj < q4 * 32) ? pj : pj + 32;
      pf = xf + ((size_t)nxt << 14) + (size_t)(g2 * 2 + pit) * 128 + pidx;
      asm volatile("global_load_dwordx2 %0, %1, off sc0" : "=v"(pv) : "v"(pf));
    }

    // ---- D: shadow work ----
    if (s >= 2 && tid >= 448 && tid < 464) {          // store y_{s-2}
      const int it = (tid - 448) >> 3, o = (tid - 448) & 7;
      float ssum = bo;
#pragma unroll
      for (int k = 0; k < 16; ++k) ssum += yred[nxt][it][o][k];
      out[((size_t)(g2 * 2 + it) * TT + (s - 2)) * OO + q4 * 8 + o] = ssum;
    }
    if (s >= 1 && tid >= 192 && tid < 448) {          // y partials for s-1
      const int l = tid - 192, it = l >> 7, idx = l & 127;
      const int o = idx & 7, jc = idx >> 3;
      YPART(uh[cur][it], yred[cur][it][o][jc]);
    }
    if (s + 1 < TT) {                                  // u+own partials, s+1
      UOWN(uh[nxt][0], a0f, a0i, a0z, a0r);
      UOWN(uh[nxt][1], a1f, a1i, a1z, a1r);
    }

    // ---- E: check spec; fast re-poll, agent escalation every 8th ----
    if (tid < 192) {
      asm volatile("s_waitcnt vmcnt(0)" : "+v"(pv) :: "memory");
      const unsigned want = (unsigned)(s + 1);
      int tries = 0;
      while ((unsigned)(pv >> 32) != want) {
        ++tries;
        if (tries & 7) {
          pv = ld_sc0(pf);
        } else {
          pv = __hip_atomic_load(pf + 32768, __ATOMIC_RELAXED,
                                 __HIP_MEMORY_SCOPE_AGENT);
        }
      }
      const int pit = (tid >= 96) ? 1 : 0;
      const int pj  = pit ? tid - 96 : tid;
      ((int*)&uh[nxt][pit][128])[pj] = (int)(unsigned)pv;
    }
    BAR_LGKM();   // B2: LDS drain only; y/out stores stay in flight
  }

  // ---- epilogue: y_{TT-2} from yred[1]; y_{TT-1} from uh[0] ----
  if (tid >= 448 && tid < 464) {
    const int it = (tid - 448) >> 3, o = (tid - 448) & 7;
    float ssum = bo;
#pragma unroll
    for (int k = 0; k < 16; ++k) ssum += yred[1][it][o][k];
    out[((size_t)(g2 * 2 + it) * TT + (TT - 2)) * OO + q4 * 8 + o] = ssum;
  }
  if (tid >= 192 && tid < 448) {
    const int l = tid - 192, it = l >> 7, idx = l & 127;
    const int o = idx & 7, jc = idx >> 3;
    YPART(uh[0][it], yred[0][it][o][jc]);
  }
  __syncthreads();
  if (tid >= 448 && tid < 464) {
    const int it = (tid - 448) >> 3, o = (tid - 448) & 7;
    float ssum = bo;
#pragma unroll
    for (int k = 0; k < 16; ++k) ssum += yred[0][it][o][k];
    out[((size_t)(g2 * 2 + it) * TT + (TT - 1)) * OO + q4 * 8 + o] = ssum;
  }
}

extern "C" void kernel_launch(void* const* d_in, const int* in_sizes, int n_in,
                              void* d_out, int out_size, void* d_ws, size_t ws_size,
                              hipStream_t stream) {
  const float* u    = (const float*)d_in[0];
  const float* x0   = (const float*)d_in[1];
  const float* kfiz = (const float*)d_in[2];
  const float* bfiz = (const float*)d_in[3];
  const float* kr   = (const float*)d_in[4];
  const float* br   = (const float*)d_in[5];
  const float* wout = (const float*)d_in[6];
  const float* bout = (const float*)d_in[7];
  float* out = (float*)d_out;
  // ws: xf[2][128][128] u64 fast lane @0 (256KB) + xa agent fallback
  // @256KB (256KB). 0xAA poison tag never matches a version in [1,2048]
  // -> no init, graph-replay safe in either lane.
  unsigned long long* xh = (unsigned long long*)d_ws;
  lstm_pair<<<dim3(256), dim3(512), 0, stream>>>(
      u, x0, kfiz, bfiz, kr, br, wout, bout, out, xh);
}

// Round 3
// 3876.415 us; speedup vs baseline: 1.3869x; 1.3869x over previous
//
#include <hip/hip_runtime.h>
#include <cstdint>
#include <cstddef>

// SingleLayerLSTM: B=128, T=2048, D=64, H=256, O=32.
// v13 = v11 (exact exchange semantics) + LATE speculative poll.
// R2 post-mortem: v12's sc0 fast lane regressed (stale L2 polls / L2 poll
// storm) but proved via FETCH_SIZE that u-sharing worked; reverted whole.
// R1 post-mortem: v11's spec load at B1+eps was null because an agent load
// SAMPLES the IC ~500cy after issue -> it sampled BEFORE partner publishes
// (issued at their C, IC-visible ~B1+400..900) landed -> always stale ->
// discovery still paid a full serial retry RTT after shadow work.
// v13: issue the one speculative agent load BETWEEN the two shadow UOWNs
// (~B1+200): samples IC ~B1+700 (fresh), returns ~B1+1200 ~= end of D.
// E then just waits vmcnt(0) and checks; retry loop remains the backstop.
// Everything else identical to v10/v11: 256 blocks x 512 thr, quad-split
// groups (g2=blk>>2, q4=blk&3), 80 fp16-pair weight VGPRs shared by both
// items, u64 tagged agent exchange (0xAA poison -> replay-safe, no init),
// raw lgkm barriers (global ops stay in flight across barriers).

#define HH 256
#define DD 64
#define TT 2048
#define OO 32

typedef _Float16 f16x2 __attribute__((ext_vector_type(2)));

__device__ __forceinline__ f16x2 b2h(int v) { return __builtin_bit_cast(f16x2, v); }
__device__ __forceinline__ int h2b(f16x2 v) { return __builtin_bit_cast(int, v); }
__device__ __forceinline__ unsigned pk32(float a, float b) {
  f16x2 v; v.x = (_Float16)a; v.y = (_Float16)b;
  return __builtin_bit_cast(unsigned, v);
}

#if __has_builtin(__builtin_amdgcn_fdot2)
__device__ __forceinline__ float fdot2(f16x2 a, f16x2 b, float c) {
  return __builtin_amdgcn_fdot2(a, b, c, false);
}
#else
__device__ __forceinline__ float fdot2(f16x2 a, f16x2 b, float c) {
  return fmaf((float)a.y, (float)b.y, fmaf((float)a.x, (float)b.x, c));
}
#endif

__device__ __forceinline__ float frcp(float x) { return __builtin_amdgcn_rcpf(x); }
__device__ __forceinline__ float sigm(float x)  { return frcp(1.0f + __expf(-x)); }
__device__ __forceinline__ float tanhf_(float x){ return 1.0f - 2.0f * frcp(1.0f + __expf(2.0f * x)); }

// LDS-only drain + raw barrier: global loads/stores stay in flight.
#define BAR_LGKM() do { \
  asm volatile("s_waitcnt lgkmcnt(0)" ::: "memory"); \
  __builtin_amdgcn_s_barrier(); \
  asm volatile("" ::: "memory"); \
} while (0)

#define XOR_ADD8(x) do { \
  x += __shfl_xor(x, 1); x += __shfl_xor(x, 2); x += __shfl_xor(x, 4); \
} while (0)

// u(8 rows) + own-h(8 rows) partial for one item; overwrites F,I,Z,R
#define UOWN(X, F, I, Z, R) do { \
  const int4 uv_ = *(const int4*)&(X)[rq * 8]; \
  const int4 ov_ = *(const int4*)&(X)[64 + rq * 8]; \
  f16x2 u0_=b2h(uv_.x),u1_=b2h(uv_.y),u2_=b2h(uv_.z),u3_=b2h(uv_.w); \
  f16x2 o0_=b2h(ov_.x),o1_=b2h(ov_.y),o2_=b2h(ov_.z),o3_=b2h(ov_.w); \
  F = fdot2(b2h(w2u[ 0]),u0_,0.0f); F = fdot2(b2h(w2u[ 1]),u1_,F); \
  F = fdot2(b2h(w2u[ 2]),u2_,F);    F = fdot2(b2h(w2u[ 3]),u3_,F); \
  F = fdot2(b2h(w2o[ 0]),o0_,F);    F = fdot2(b2h(w2o[ 1]),o1_,F); \
  F = fdot2(b2h(w2o[ 2]),o2_,F);    F = fdot2(b2h(w2o[ 3]),o3_,F); \
  I = fdot2(b2h(w2u[ 4]),u0_,0.0f); I = fdot2(b2h(w2u[ 5]),u1_,I); \
  I = fdot2(b2h(w2u[ 6]),u2_,I);    I = fdot2(b2h(w2u[ 7]),u3_,I); \
  I = fdot2(b2h(w2o[ 4]),o0_,I);    I = fdot2(b2h(w2o[ 5]),o1_,I); \
  I = fdot2(b2h(w2o[ 6]),o2_,I);    I = fdot2(b2h(w2o[ 7]),o3_,I); \
  Z = fdot2(b2h(w2u[ 8]),u0_,0.0f); Z = fdot2(b2h(w2u[ 9]),u1_,Z); \
  Z = fdot2(b2h(w2u[10]),u2_,Z);    Z = fdot2(b2h(w2u[11]),u3_,Z); \
  Z = fdot2(b2h(w2o[ 8]),o0_,Z);    Z = fdot2(b2h(w2o[ 9]),o1_,Z); \
  Z = fdot2(b2h(w2o[10]),o2_,Z);    Z = fdot2(b2h(w2o[11]),o3_,Z); \
  R = fdot2(b2h(w2u[12]),u0_,0.0f); R = fdot2(b2h(w2u[13]),u1_,R); \
  R = fdot2(b2h(w2u[14]),u2_,R);    R = fdot2(b2h(w2u[15]),u3_,R); \
  R = fdot2(b2h(w2o[12]),o0_,R);    R = fdot2(b2h(w2o[13]),o1_,R); \
  R = fdot2(b2h(w2o[14]),o2_,R);    R = fdot2(b2h(w2o[15]),o3_,R); \
} while (0)

// partner-h (24 rows) accumulate into F,I,Z,R
#define PDOT(X, F, I, Z, R) do { \
  const int4* pp_ = (const int4*)&(X)[128 + rq * 24]; \
  int4 v0_ = pp_[0], v1_ = pp_[1], v2_ = pp_[2]; \
  f16x2 h0_=b2h(v0_.x),h1_=b2h(v0_.y),h2_ =b2h(v0_.z),h3_ =b2h(v0_.w); \
  f16x2 h4_=b2h(v1_.x),h5_=b2h(v1_.y),h6_ =b2h(v1_.z),h7_ =b2h(v1_.w); \
  f16x2 h8_=b2h(v2_.x),h9_=b2h(v2_.y),h10_=b2h(v2_.z),h11_=b2h(v2_.w); \
  F=fdot2(b2h(w2p[ 0]),h0_,F); F=fdot2(b2h(w2p[ 1]),h1_,F); \
  F=fdot2(b2h(w2p[ 2]),h2_,F); F=fdot2(b2h(w2p[ 3]),h3_,F); \
  F=fdot2(b2h(w2p[ 4]),h4_,F); F=fdot2(b2h(w2p[ 5]),h5_,F); \
  F=fdot2(b2h(w2p[ 6]),h6_,F); F=fdot2(b2h(w2p[ 7]),h7_,F); \
  F=fdot2(b2h(w2p[ 8]),h8_,F); F=fdot2(b2h(w2p[ 9]),h9_,F); \
  F=fdot2(b2h(w2p[10]),h10_,F);F=fdot2(b2h(w2p[11]),h11_,F); \
  I=fdot2(b2h(w2p[12]),h0_,I); I=fdot2(b2h(w2p[13]),h1_,I); \
  I=fdot2(b2h(w2p[14]),h2_,I); I=fdot2(b2h(w2p[15]),h3_,I); \
  I=fdot2(b2h(w2p[16]),h4_,I); I=fdot2(b2h(w2p[17]),h5_,I); \
  I=fdot2(b2h(w2p[18]),h6_,I); I=fdot2(b2h(w2p[19]),h7_,I); \
  I=fdot2(b2h(w2p[20]),h8_,I); I=fdot2(b2h(w2p[21]),h9_,I); \
  I=fdot2(b2h(w2p[22]),h10_,I);I=fdot2(b2h(w2p[23]),h11_,I); \
  Z=fdot2(b2h(w2p[24]),h0_,Z); Z=fdot2(b2h(w2p[25]),h1_,Z); \
  Z=fdot2(b2h(w2p[26]),h2_,Z); Z=fdot2(b2h(w2p[27]),h3_,Z); \
  Z=fdot2(b2h(w2p[28]),h4_,Z); Z=fdot2(b2h(w2p[29]),h5_,Z); \
  Z=fdot2(b2h(w2p[30]),h6_,Z); Z=fdot2(b2h(w2p[31]),h7_,Z); \
  Z=fdot2(b2h(w2p[32]),h8_,Z); Z=fdot2(b2h(w2p[33]),h9_,Z); \
  Z=fdot2(b2h(w2p[34]),h10_,Z);Z=fdot2(b2h(w2p[35]),h11_,Z); \
  R=fdot2(b2h(w2p[36]),h0_,R); R=fdot2(b2h(w2p[37]),h1_,R); \
  R=fdot2(b2h(w2p[38]),h2_,R); R=fdot2(b2h(w2p[39]),h3_,R); \
  R=fdot2(b2h(w2p[40]),h4_,R); R=fdot2(b2h(w2p[41]),h5_,R); \
  R=fdot2(b2h(w2p[42]),h6_,R); R=fdot2(b2h(w2p[43]),h7_,R); \
  R=fdot2(b2h(w2p[44]),h8_,R); R=fdot2(b2h(w2p[45]),h9_,R); \
  R=fdot2(b2h(w2p[46]),h10_,R);R=fdot2(b2h(w2p[47]),h11_,R); \
} while (0)

// y-partials for one item from the permuted h region of X
#define YPART(X, OUTSLOT) do { \
  const int2* hq_ = (const int2*)&(X)[64 + jc * 16]; \
  int2 h0_ = hq_[0], h1_ = hq_[1], h2_ = hq_[2], h3_ = hq_[3]; \
  const int4* wp_ = (const int4*)&wopk[(jc * 8 + o) * 8]; \
  int4 wa_ = wp_[0], wb_ = wp_[1]; \
  float ya_ = 0.0f; \
  ya_ = fdot2(b2h(wa_.x), b2h(h0_.x), ya_); \
  ya_ = fdot2(b2h(wa_.y), b2h(h0_.y), ya_); \
  ya_ = fdot2(b2h(wa_.z), b2h(h1_.x), ya_); \
  ya_ = fdot2(b2h(wa_.w), b2h(h1_.y), ya_); \
  ya_ = fdot2(b2h(wb_.x), b2h(h2_.x), ya_); \
  ya_ = fdot2(b2h(wb_.y), b2h(h2_.y), ya_); \
  ya_ = fdot2(b2h(wb_.z), b2h(h3_.x), ya_); \
  ya_ = fdot2(b2h(wb_.w), b2h(h3_.y), ya_); \
  OUTSLOT = ya_; \
} while (0)

__global__ __launch_bounds__(512, 2)
void lstm_pair(const float* __restrict__ u,    const float* __restrict__ x0,
               const float* __restrict__ kfiz, const float* __restrict__ bfiz,
               const float* __restrict__ kr,   const float* __restrict__ br,
               const float* __restrict__ wout, const float* __restrict__ bout,
               float* __restrict__ out, unsigned long long* __restrict__ xh)
{
  const int tid = threadIdx.x;
  const int g2  = blockIdx.x >> 2;         // item pair: items 2g2, 2g2+1
  const int q4  = blockIdx.x & 3;          // quarter
  const int c   = tid >> 3;                // channel within quarter [0,64)
  const int rq  = tid & 7;                 // row slice
  const int cg  = q4 * 64 + c;             // global channel

  // per (parity,item): [0,64) u | [64,128) own h | [128,320) partner h (P-order)
  __shared__ __align__(16) _Float16 uh[2][2][320];
  __shared__ float yred[2][2][8][17];
  __shared__ __align__(16) int wopk[1024];

  // ---- register-resident weights (80 pairs, shared by both items) ----
  int w2u[16], w2o[16], w2p[48];
#pragma unroll
  for (int g = 0; g < 4; ++g) {
    const float* colp = (g < 3) ? (kfiz + g * HH + cg) : (kr + cg);
    const int cst = (g < 3) ? 3 * HH : HH;
#pragma unroll
    for (int k = 0; k < 4; ++k) {
      f16x2 v;
      v.x = (_Float16)colp[(rq * 8 + 2 * k    ) * cst];
      v.y = (_Float16)colp[(rq * 8 + 2 * k + 1) * cst];
      w2u[g * 4 + k] = h2b(v);
      f16x2 w;
      w.x = (_Float16)colp[(DD + q4 * 64 + rq * 8 + 2 * k    ) * cst];
      w.y = (_Float16)colp[(DD + q4 * 64 + rq * 8 + 2 * k + 1) * cst];
      w2o[g * 4 + k] = h2b(w);
    }
#pragma unroll
    for (int m = 0; m < 12; ++m) {
      const int j0 = rq * 24 + 2 * m, j1 = j0 + 1;
      const int r0 = DD + (j0 < q4 * 64 ? j0 : j0 + 64);
      const int r1 = DD + (j1 < q4 * 64 ? j1 : j1 + 64);
      f16x2 v;
      v.x = (_Float16)colp[r0 * cst];
      v.y = (_Float16)colp[r1 * cst];
      w2p[g * 12 + m] = h2b(v);
    }
  }
  const float bf_ = bfiz[0 * HH + cg];
  const float bi_ = bfiz[1 * HH + cg];
  const float bz_ = bfiz[2 * HH + cg];
  const float br_ = br[cg];

  // ---- W_out staged permuted (block's 8 out cols; item-invariant) ----
  for (int t = tid; t < 1024; t += 512) {
    const int jc = t >> 6, o = (t >> 3) & 7, k = t & 7;
    const int pos0 = jc * 16 + 2 * k, pos1 = pos0 + 1;
    const int ch0 = (pos0 < 64) ? q4 * 64 + pos0
                                : ((pos0 - 64) < q4 * 64 ? pos0 - 64 : pos0);
    const int ch1 = (pos1 < 64) ? q4 * 64 + pos1
                                : ((pos1 - 64) < q4 * 64 ? pos1 - 64 : pos1);
    f16x2 v;
    v.x = (_Float16)wout[ch0 * OO + q4 * 8 + o];
    v.y = (_Float16)wout[ch1 * OO + q4 * 8 + o];
    wopk[t] = h2b(v);
  }
  const float bo = (tid >= 448 && tid < 464) ? bout[q4 * 8 + ((tid - 448) & 7)] : 0.0f;

  // ---- state init ----
  float cs0 = x0[(size_t)(g2 * 2 + 0) * 512 + 256 + cg];
  float cs1 = x0[(size_t)(g2 * 2 + 1) * 512 + 256 + cg];
  {  // h0, permuted; all 512 lanes cover 2 items x 256 ch
    const int it = tid >> 8, ch = tid & 255;
    const int pos = (ch >= q4 * 64 && ch < q4 * 64 + 64)
                        ? 64 + (ch - q4 * 64)
                        : 128 + (ch < q4 * 64 ? ch : ch - 64);
    uh[0][it][pos] = (_Float16)x0[(size_t)(g2 * 2 + it) * 512 + ch];
  }
  if (tid >= 192 && tid < 320) {   // u_0
    const int l = tid - 192;
    uh[0][l >> 6][l & 63] = (_Float16)u[((size_t)(g2 * 2 + (l >> 6)) * TT) * DD + (l & 63)];
  }
  __syncthreads();

  float a0f, a0i, a0z, a0r, a1f, a1i, a1z, a1r;
  UOWN(uh[0][0], a0f, a0i, a0z, a0r);
  UOWN(uh[0][1], a1f, a1i, a1z, a1r);

  for (int s = 0; s < TT; ++s) {
    const int cur = s & 1, nxt = cur ^ 1;

    // u_{s+1} issued early (lanes 192..319)
    float un = 0.0f;
    if (tid >= 192 && tid < 320 && s + 1 < TT) {
      const int l = tid - 192;
      un = u[((size_t)(g2 * 2 + (l >> 6)) * TT + s + 1) * DD + (l & 63)];
    }

    // ---- A: partner dots, both items ----
    PDOT(uh[cur][0], a0f, a0i, a0z, a0r);
    PDOT(uh[cur][1], a1f, a1i, a1z, a1r);

    // ---- B: reduce + activations ----
    XOR_ADD8(a0f); XOR_ADD8(a0i); XOR_ADD8(a0z); XOR_ADD8(a0r);
    XOR_ADD8(a1f); XOR_ADD8(a1i); XOR_ADD8(a1z); XOR_ADD8(a1r);
    const float f0 = sigm(a0f + bf_), i0 = sigm(a0i + bi_);
    const float z0 = sigm(a0z + bz_), r0 = tanhf_(a0r + br_);
    cs0 = f0 * cs0 + i0 * r0;
    const float hn0 = z0 * tanhf_(cs0);
    const float f1 = sigm(a1f + bf_), i1 = sigm(a1i + bi_);
    const float z1 = sigm(a1z + bz_), r1 = tanhf_(a1r + br_);
    cs1 = f1 * cs1 + i1 * r1;
    const float hn1 = z1 * tanhf_(cs1);

    // ---- C: publish (u64, 2 ch/word) + own-h LDS + u_{s+1} LDS ----
    const float hn0n = __shfl_down(hn0, 8);   // channel c+1's value (rq kept)
    const float hn1n = __shfl_down(hn1, 8);
    if (rq == 0) {
      uh[nxt][0][64 + c] = (_Float16)hn0;
      uh[nxt][1][64 + c] = (_Float16)hn1;
      if (!(c & 1)) {
        const int pair = q4 * 32 + (c >> 1);
        const unsigned long long tag = (unsigned long long)(s + 1) << 32;
        __hip_atomic_store(&xh[((size_t)nxt * 128 + g2 * 2 + 0) * 128 + pair],
                           tag | pk32(hn0, hn0n),
                           __ATOMIC_RELAXED, __HIP_MEMORY_SCOPE_AGENT);
        __hip_atomic_store(&xh[((size_t)nxt * 128 + g2 * 2 + 1) * 128 + pair],
                           tag | pk32(hn1, hn1n),
                           __ATOMIC_RELAXED, __HIP_MEMORY_SCOPE_AGENT);
      }
    }
    if (tid >= 192 && tid < 320 && s + 1 < TT) {
      const int l = tid - 192;
      uh[nxt][l >> 6][l & 63] = (_Float16)un;
    }
    BAR_LGKM();   // B1: LDS drain only; publish stores stay in flight

    // ---- D: shadow work, with the spec poll issued MID-D ----
    if (s >= 2 && tid >= 448 && tid < 464) {          // store y_{s-2}
      const int it = (tid - 448) >> 3, o = (tid - 448) & 7;
      float ssum = bo;
#pragma unroll
      for (int k = 0; k < 16; ++k) ssum += yred[nxt][it][o][k];
      out[((size_t)(g2 * 2 + it) * TT + (s - 2)) * OO + q4 * 8 + o] = ssum;
    }
    if (s >= 1 && tid >= 192 && tid < 448) {          // y partials for s-1
      const int l = tid - 192, it = l >> 7, idx = l & 127;
      const int o = idx & 7, jc = idx >> 3;
      YPART(uh[cur][it], yred[cur][it][o][jc]);
    }
    unsigned long long pv = 0;
    const unsigned long long* pf = nullptr;
    if (tid < 192) {
      const int pit = (tid >= 96) ? 1 : 0;
      const int pj  = pit ? tid - 96 : tid;
      const int pidx = (pj < q4 * 32) ? pj : pj + 32;
      pf = xh + ((size_t)nxt << 14) + (size_t)(g2 * 2 + pit) * 128 + pidx;
    }
    if (s + 1 < TT) {                                  // u+own partials s+1, item0
      UOWN(uh[nxt][0], a0f, a0i, a0z, a0r);
    }
    if (tid < 192) {
      // LATE spec issue (~B1+200): samples IC after partner publishes land,
      // returns ~end of D. sc0 sc1 = system-scope load, bypass L1+L2.
      asm volatile("global_load_dwordx2 %0, %1, off sc0 sc1"
                   : "=v"(pv) : "v"(pf));
    }
    if (s + 1 < TT) {                                  // u+own partials s+1, item1
      UOWN(uh[nxt][1], a1f, a1i, a1z, a1r);
    }

    // ---- E: check spec; serial agent re-poll only if stale ----
    if (tid < 192) {
      asm volatile("s_waitcnt vmcnt(0)" : "+v"(pv) :: "memory");
      const unsigned want = (unsigned)(s + 1);
      while ((unsigned)(pv >> 32) != want)
        pv = __hip_atomic_load(pf, __ATOMIC_RELAXED, __HIP_MEMORY_SCOPE_AGENT);
      const int pit = (tid >= 96) ? 1 : 0;
      const int pj  = pit ? tid - 96 : tid;
      ((int*)&uh[nxt][pit][128])[pj] = (int)(unsigned)pv;
    }
    BAR_LGKM();   // B2: LDS drain only; y/out stores stay in flight
  }

  // ---- epilogue: y_{TT-2} from yred[1]; y_{TT-1} from uh[0] ----
  if (tid >= 448 && tid < 464) {
    const int it = (tid - 448) >> 3, o = (tid - 448) & 7;
    float ssum = bo;
#pragma unroll
    for (int k = 0; k < 16; ++k) ssum += yred[1][it][o][k];
    out[((size_t)(g2 * 2 + it) * TT + (TT - 2)) * OO + q4 * 8 + o] = ssum;
  }
  if (tid >= 192 && tid < 448) {
    const int l = tid - 192, it = l >> 7, idx = l & 127;
    const int o = idx & 7, jc = idx >> 3;
    YPART(uh[0][it], yred[0][it][o][jc]);
  }
  __syncthreads();
  if (tid >= 448 && tid < 464) {
    const int it = (tid - 448) >> 3, o = (tid - 448) & 7;
    float ssum = bo;
#pragma unroll
    for (int k = 0; k < 16; ++k) ssum += yred[0][it][o][k];
    out[((size_t)(g2 * 2 + it) * TT + (TT - 1)) * OO + q4 * 8 + o] = ssum;
  }
}

extern "C" void kernel_launch(void* const* d_in, const int* in_sizes, int n_in,
                              void* d_out, int out_size, void* d_ws, size_t ws_size,
                              hipStream_t stream) {
  const float* u    = (const float*)d_in[0];
  const float* x0   = (const float*)d_in[1];
  const float* kfiz = (const float*)d_in[2];
  const float* bfiz = (const float*)d_in[3];
  const float* kr   = (const float*)d_in[4];
  const float* br   = (const float*)d_in[5];
  const float* wout = (const float*)d_in[6];
  const float* bout = (const float*)d_in[7];
  float* out = (float*)d_out;
  // ws: xh[2 parity][128 item][128 pair] u64 = 256 KB. 0xAA poison -> tag
  // 0xAAAAAAAA never matches a version in [1,2048] -> no init, replay-safe.
  unsigned long long* xh = (unsigned long long*)d_ws;
  lstm_pair<<<dim3(256), dim3(512), 0, stream>>>(
      u, x0, kfiz, bfiz, kr, br, wout, bout, out, xh);
}